// Round 7
// baseline (274.176 us; speedup 1.0000x reference)
//
#include <hip/hip_runtime.h>
#include <cstdint>
#include <cstddef>

// ---------- types ----------
typedef __bf16 bf16;
typedef __bf16 bf16x8 __attribute__((ext_vector_type(8)));
typedef __bf16 bf16x4 __attribute__((ext_vector_type(4)));
typedef __bf16 bf16x2 __attribute__((ext_vector_type(2)));
typedef float  floatx4 __attribute__((ext_vector_type(4)));

typedef __attribute__((address_space(1))) void gvoid_t;
typedef __attribute__((address_space(3))) void lvoid_t;

#define MFMA16(a, b, c) __builtin_amdgcn_mfma_f32_16x16x32_bf16((a), (b), (c), 0, 0, 0)

#if __has_builtin(__builtin_amdgcn_exp2f)
#define EXP2(x) __builtin_amdgcn_exp2f(x)
#else
#define EXP2(x) exp2f(x)
#endif

// B=2, S=2048, D=1024, H=16, DH=64; tokens NT=4096; E3=3072
#define S_TOK 2048
#define E3 3072
#define DMODEL 1024

// ---------- fp32 -> bf16 convert ----------
__global__ __launch_bounds__(256) void cvt_f32_bf16(const float* __restrict__ s,
                                                    bf16* __restrict__ d, int n) {
  int i = (blockIdx.x * 256 + threadIdx.x) * 8;
  if (i >= n) return;
  const float4* p = (const float4*)(s + i);
  float4 a = p[0], b = p[1];
  bf16x8 o;
  o[0] = (bf16)a.x; o[1] = (bf16)a.y; o[2] = (bf16)a.z; o[3] = (bf16)a.w;
  o[4] = (bf16)b.x; o[5] = (bf16)b.y; o[6] = (bf16)b.z; o[7] = (bf16)b.w;
  *(bf16x8*)(d + i) = o;
}

// ---------- W_qkv convert with softmax scale pre-folded into Q rows ----------
__global__ __launch_bounds__(256) void cvt_wqkv(const float* __restrict__ s,
                                                bf16* __restrict__ d, int n) {
  int i = (blockIdx.x * 256 + threadIdx.x) * 8;
  if (i >= n) return;
  int row = i >> 10;  // D=1024 per row
  float sc = ((row % 192) < 64) ? 0.18033688011f : 1.0f;
  const float4* p = (const float4*)(s + i);
  float4 a = p[0], b = p[1];
  bf16x8 o;
  o[0] = (bf16)(a.x * sc); o[1] = (bf16)(a.y * sc);
  o[2] = (bf16)(a.z * sc); o[3] = (bf16)(a.w * sc);
  o[4] = (bf16)(b.x * sc); o[5] = (bf16)(b.y * sc);
  o[6] = (bf16)(b.z * sc); o[7] = (bf16)(b.w * sc);
  *(bf16x8*)(d + i) = o;
}

// ---------- async global->LDS, 16B per lane ----------
__device__ __forceinline__ void gl_lds16(const bf16* g, bf16* l) {
  __builtin_amdgcn_global_load_lds((gvoid_t*)g, (lvoid_t*)l, 16, 0, 0);
}

// ---------- GEMM: C[m][n] = sum_k A[m][k] * Bt[n][k]  (m97 structure) ----------
template <bool OUT_BF16>
__global__ __launch_bounds__(256) void gemm_bt(const bf16* __restrict__ A,
                                               const bf16* __restrict__ Bt,
                                               void* __restrict__ Cv,
                                               int M, int N, int K) {
  __shared__ bf16 sA[128 * 32];
  __shared__ bf16 sB[128 * 32];
  const int tid = threadIdx.x;
  const int wv = tid >> 6, lane = tid & 63;
  const int wr = wv >> 1, wc = wv & 1;
  const int lrow = lane & 15, lgrp = lane >> 4;
  const int R0 = blockIdx.y * 128, C0 = blockIdx.x * 128;

  floatx4 acc[4][4] = {};

  const bf16* gA = A + (size_t)(R0 + wv * 32 + (lane >> 2)) * K + (lane & 3) * 8;
  const bf16* gB = Bt + (size_t)(C0 + wv * 32 + (lane >> 2)) * K + (lane & 3) * 8;
  bf16* lA = sA + wv * 1024;
  bf16* lB = sB + wv * 1024;
  const size_t rowstep = (size_t)16 * K;

  for (int k0 = 0; k0 < K; k0 += 32) {
    gl_lds16(gA + k0, lA);
    gl_lds16(gA + k0 + rowstep, lA + 512);
    gl_lds16(gB + k0, lB);
    gl_lds16(gB + k0 + rowstep, lB + 512);
    __syncthreads();
    bf16x8 af[4], bfr[4];
#pragma unroll
    for (int i = 0; i < 4; i++)
      af[i] = *(const bf16x8*)&sA[(wr * 64 + i * 16 + lrow) * 32 + lgrp * 8];
#pragma unroll
    for (int j = 0; j < 4; j++)
      bfr[j] = *(const bf16x8*)&sB[(wc * 64 + j * 16 + lrow) * 32 + lgrp * 8];
#pragma unroll
    for (int i = 0; i < 4; i++)
#pragma unroll
      for (int j = 0; j < 4; j++)
        acc[i][j] = MFMA16(af[i], bfr[j], acc[i][j]);
    __syncthreads();
  }

  const int rbase = R0 + wr * 64 + lgrp * 4;
  const int cbase = C0 + wc * 64 + lrow;
  if (OUT_BF16) {
    bf16* C = (bf16*)Cv;
#pragma unroll
    for (int i = 0; i < 4; i++)
#pragma unroll
      for (int j = 0; j < 4; j++)
#pragma unroll
        for (int r = 0; r < 4; r++)
          C[(size_t)(rbase + i * 16 + r) * N + cbase + j * 16] = (bf16)acc[i][j][r];
  } else {
    float* C = (float*)Cv;
#pragma unroll
    for (int i = 0; i < 4; i++)
#pragma unroll
      for (int j = 0; j < 4; j++)
#pragma unroll
        for (int r = 0; r < 4; r++)
          C[(size_t)(rbase + i * 16 + r) * N + cbase + j * 16] = acc[i][j][r];
  }
}

// ---------- V transpose with sigma permutation baked in ----------
__global__ __launch_bounds__(256) void transpose_v(const bf16* __restrict__ qkv,
                                                   bf16* __restrict__ Vt) {
  __shared__ bf16 sT[64 * 72];
  const int tid = threadIdx.x;
  const int b = blockIdx.z, h = blockIdx.y, s0 = blockIdx.x * 64;
  const bf16* vsrc = qkv + (size_t)(b * S_TOK + s0) * E3 + h * 192 + 128;
#pragma unroll
  for (int j = 0; j < 8; j++) {
    int idx = tid + 256 * j;
    int sl = idx & 63, dp = idx >> 6;
    unsigned u = *(const unsigned*)(vsrc + (size_t)sl * E3 + 2 * dp);
    sT[(2 * dp) * 72 + sl] = __builtin_bit_cast(bf16, (unsigned short)(u & 0xffffu));
    sT[(2 * dp + 1) * 72 + sl] = __builtin_bit_cast(bf16, (unsigned short)(u >> 16));
  }
  __syncthreads();
  bf16* vdst = Vt + ((size_t)(b * 16 + h) * 64) * S_TOK + s0;
#pragma unroll
  for (int j = 0; j < 2; j++) {
    int idx = tid + 256 * j;
    int d = idx >> 3, sc8 = (idx & 7) * 8;
    bf16x8 o;
#pragma unroll
    for (int m2 = 0; m2 < 8; m2++) {
      int sp = sc8 + m2;
      int ss = (sp & ~31) | ((sp >> 1) & 15) | ((sp & 1) << 4);
      o[m2] = sT[d * 72 + ss];
    }
    *(bf16x8*)(vdst + (size_t)d * S_TOK + sc8) = o;
  }
}

// ---------- attention v6: v5 + register ping-pong K/V prefetch ----------
__device__ __forceinline__ void load_kv(const bf16* __restrict__ kp,
                                        const bf16* __restrict__ vp,
                                        int kt, int lrow, int lgrp,
                                        bf16x8 (&kf)[2][2], bf16x8 (&vf)[4]) {
#pragma unroll
  for (int t = 0; t < 2; t++)
#pragma unroll
    for (int dh = 0; dh < 2; dh++)
      kf[t][dh] = *(const bf16x8*)(kp + (size_t)(kt * 32 + t * 16 + lrow) * E3 + dh * 32 + lgrp * 8);
#pragma unroll
  for (int dt = 0; dt < 4; dt++)
    vf[dt] = *(const bf16x8*)(vp + (size_t)(dt * 16 + lrow) * S_TOK + kt * 32 + lgrp * 8);
}

__device__ __forceinline__ void attn_tile(const bf16x8 (&qa)[2][2],
                                          const bf16x8 (&kf)[2][2],
                                          const bf16x8 (&vf)[4],
                                          floatx4 (&O)[2][4], floatx4 (&lacc)[2],
                                          const bf16x8& ones,
                                          bf16* __restrict__ sPp,
                                          int lrow, int lgrp) {
  // QK^T (Q pre-scaled), exp2, pack P in A-layout order (sigma cols 2c,2c+1)
#pragma unroll
  for (int rt = 0; rt < 2; rt++) {
    floatx4 sc0 = {0.f, 0.f, 0.f, 0.f}, sc1 = {0.f, 0.f, 0.f, 0.f};
    sc0 = MFMA16(qa[rt][0], kf[0][0], sc0);
    sc0 = MFMA16(qa[rt][1], kf[0][1], sc0);
    sc1 = MFMA16(qa[rt][0], kf[1][0], sc1);
    sc1 = MFMA16(qa[rt][1], kf[1][1], sc1);
#pragma unroll
    for (int r = 0; r < 4; r++) {
      bf16x2 h2;
      h2[0] = (bf16)EXP2(sc0[r]);
      h2[1] = (bf16)EXP2(sc1[r]);
      *(unsigned*)(sPp + rt * 640 + (lgrp * 4 + r) * 40 + lrow * 2) =
          __builtin_bit_cast(unsigned, h2);
    }
  }
  // P back as A-frags; PV + row-sum via ones-column MFMA
#pragma unroll
  for (int rt = 0; rt < 2; rt++) {
    bf16x8 pf = *(const bf16x8*)(sPp + rt * 640 + lrow * 40 + lgrp * 8);
#pragma unroll
    for (int dt = 0; dt < 4; dt++) O[rt][dt] = MFMA16(pf, vf[dt], O[rt][dt]);
    lacc[rt] = MFMA16(pf, ones, lacc[rt]);
  }
}

__global__ __launch_bounds__(256, 3) void attn(const bf16* __restrict__ qkv,
                                               const bf16* __restrict__ Vt,
                                               bf16* __restrict__ vals) {
  __shared__ bf16 sP[4 * 2 * 2 * 640];  // [wave][parity][rowtile][16 x stride40] 20 KB
  __shared__ float redO[4][16 * 72];    // per-wave partial O, rowtile-at-a-time, 18.4 KB
  __shared__ float redl[4][2][16];      // [wave][rowtile][row] partial row-sums, 0.5 KB

  const int tid = threadIdx.x;
  const int wv = tid >> 6, lane = tid & 63;
  const int wrow = wv >> 1, wkey = wv & 1;
  const int lrow = lane & 15, lgrp = lane >> 4;
  const int b = blockIdx.z, h = blockIdx.y;
  const int qbase = blockIdx.x * 64;

  const bf16* qp = qkv + (size_t)(b * S_TOK + qbase + wrow * 32) * E3 + h * 192;
  const bf16* kp = qkv + (size_t)(b * S_TOK) * E3 + h * 192 + 64;
  const bf16* vp = Vt + (size_t)((b * 16 + h) * 64) * S_TOK;
  bf16* sPw = sP + wv * 1280;

  // Q A-fragments hoisted to registers: A[m=lane&15][k=lgrp*8+j]
  bf16x8 qa[2][2];
#pragma unroll
  for (int rt = 0; rt < 2; rt++)
#pragma unroll
    for (int dh = 0; dh < 2; dh++)
      qa[rt][dh] = *(const bf16x8*)(qp + (size_t)(rt * 16 + lrow) * E3 + dh * 32 + lgrp * 8);

  floatx4 O[2][4] = {};
  floatx4 lacc[2] = {};
  bf16x8 ones;
  const bf16 one1 = (bf16)1.0f;
#pragma unroll
  for (int j = 0; j < 8; j++) ones[j] = one1;

  const int kt0 = wkey * 32;
  bf16x8 kfa[2][2], vfa[4], kfb[2][2], vfb[4];
  load_kv(kp, vp, kt0, lrow, lgrp, kfa, vfa);
#pragma unroll 1
  for (int kt = kt0; kt < kt0 + 32; kt += 2) {
    load_kv(kp, vp, kt + 1, lrow, lgrp, kfb, vfb);       // prefetch B while computing A
    attn_tile(qa, kfa, vfa, O, lacc, ones, sPw, lrow, lgrp);
    load_kv(kp, vp, (kt + 2 < kt0 + 32) ? kt + 2 : kt0,  // prefetch next A (tail: dummy)
            lrow, lgrp, kfa, vfa);
    attn_tile(qa, kfb, vfb, O, lacc, ones, sPw + 1280 * 4, lrow, lgrp);
  }

  // ---- pairwise cross-wave reduction (waves 2p, 2p+1 share rows), normalize ----
  if (lrow == 0) {
#pragma unroll
    for (int rt = 0; rt < 2; rt++)
#pragma unroll
      for (int r = 0; r < 4; r++)
        redl[wv][rt][lgrp * 4 + r] = lacc[rt][r];
  }
  bf16* vout = vals + (size_t)(b * S_TOK + qbase) * DMODEL + h * 64;
#pragma unroll
  for (int rt = 0; rt < 2; rt++) {  // fully unrolled: rt compile-time, O stays in regs
    __syncthreads();
#pragma unroll
    for (int dt = 0; dt < 4; dt++)
#pragma unroll
      for (int r = 0; r < 4; r++)
        redO[wv][(lgrp * 4 + r) * 72 + dt * 16 + lrow] = O[rt][dt][r];
    __syncthreads();
    const int p = tid >> 7, t2 = tid & 127;
    const int row = t2 >> 3, col = (t2 & 7) * 8;
    float ls = redl[2 * p][rt][row] + redl[2 * p + 1][rt][row];
    float rinv = __builtin_amdgcn_rcpf(ls);
    const float4 a0 = *(const float4*)&redO[2 * p][row * 72 + col];
    const float4 a1 = *(const float4*)&redO[2 * p][row * 72 + col + 4];
    const float4 b0 = *(const float4*)&redO[2 * p + 1][row * 72 + col];
    const float4 b1 = *(const float4*)&redO[2 * p + 1][row * 72 + col + 4];
    bf16x8 o;
    o[0] = (bf16)((a0.x + b0.x) * rinv); o[1] = (bf16)((a0.y + b0.y) * rinv);
    o[2] = (bf16)((a0.z + b0.z) * rinv); o[3] = (bf16)((a0.w + b0.w) * rinv);
    o[4] = (bf16)((a1.x + b1.x) * rinv); o[5] = (bf16)((a1.y + b1.y) * rinv);
    o[6] = (bf16)((a1.z + b1.z) * rinv); o[7] = (bf16)((a1.w + b1.w) * rinv);
    *(bf16x8*)(vout + (size_t)(p * 32 + rt * 16 + row) * DMODEL + col) = o;
  }
}

// ---------- host ----------
extern "C" void kernel_launch(void* const* d_in, const int* in_sizes, int n_in,
                              void* d_out, int out_size, void* d_ws, size_t ws_size,
                              hipStream_t stream) {
  const float* X = (const float*)d_in[0];     // (2,2048,1024)
  const float* Wqkv = (const float*)d_in[1];  // (3072,1024)
  const float* Wout = (const float*)d_in[2];  // (1024,1024)
  float* out = (float*)d_out;                 // (2,2048,1024)

  char* ws = (char*)d_ws;
  bf16* Xb = (bf16*)(ws);                          //  8 MB
  bf16* Wqb = (bf16*)(ws + ((size_t)8 << 20));     //  6 MB
  bf16* Wob = (bf16*)(ws + ((size_t)14 << 20));    //  2 MB
  bf16* qkvb = (bf16*)(ws + ((size_t)16 << 20));   // 24 MB (4096 x 3072)
  bf16* Vt = (bf16*)(ws + ((size_t)40 << 20));     //  8 MB (2*16*64 x 2048)
  bf16* vals = (bf16*)(ws + ((size_t)48 << 20));   //  8 MB (4096 x 1024)

  cvt_f32_bf16<<<4194304 / 2048, 256, 0, stream>>>(X, Xb, 4194304);
  cvt_wqkv<<<3145728 / 2048, 256, 0, stream>>>(Wqkv, Wqb, 3145728);
  cvt_f32_bf16<<<1048576 / 2048, 256, 0, stream>>>(Wout, Wob, 1048576);

  // qkv = X @ Wqkv^T : (4096,1024)x(3072,1024)^T -> (4096,3072) bf16
  gemm_bt<true><<<dim3(24, 32), 256, 0, stream>>>(Xb, Wqb, qkvb, 4096, 3072, 1024);

  transpose_v<<<dim3(32, 16, 2), 256, 0, stream>>>(qkvb, Vt);

  attn<<<dim3(32, 16, 2), 256, 0, stream>>>(qkvb, Vt, vals);

  // out = vals @ Wout^T : (4096,1024)x(1024,1024)^T -> (4096,1024) fp32
  gemm_bt<false><<<dim3(8, 32), 256, 0, stream>>>(vals, Wob, out, 4096, 1024, 1024);
}

// Round 8
// 202.902 us; speedup vs baseline: 1.3513x; 1.3513x over previous
//
#include <hip/hip_runtime.h>
#include <cstdint>
#include <cstddef>

// ---------- types ----------
typedef __bf16 bf16;
typedef __bf16 bf16x8 __attribute__((ext_vector_type(8)));
typedef __bf16 bf16x2 __attribute__((ext_vector_type(2)));
typedef float  floatx4 __attribute__((ext_vector_type(4)));

typedef __attribute__((address_space(1))) void gvoid_t;
typedef __attribute__((address_space(3))) void lvoid_t;

#define MFMA16(a, b, c) __builtin_amdgcn_mfma_f32_16x16x32_bf16((a), (b), (c), 0, 0, 0)

#if __has_builtin(__builtin_amdgcn_exp2f)
#define EXP2(x) __builtin_amdgcn_exp2f(x)
#else
#define EXP2(x) exp2f(x)
#endif

// B=2, S=2048, D=1024, H=16, DH=64; tokens NT=4096; E3=3072
#define S_TOK 2048
#define E3 3072
#define DMODEL 1024

// ---------- fp32 -> bf16 convert ----------
__global__ __launch_bounds__(256) void cvt_f32_bf16(const float* __restrict__ s,
                                                    bf16* __restrict__ d, int n) {
  int i = (blockIdx.x * 256 + threadIdx.x) * 8;
  if (i >= n) return;
  const float4* p = (const float4*)(s + i);
  float4 a = p[0], b = p[1];
  bf16x8 o;
  o[0] = (bf16)a.x; o[1] = (bf16)a.y; o[2] = (bf16)a.z; o[3] = (bf16)a.w;
  o[4] = (bf16)b.x; o[5] = (bf16)b.y; o[6] = (bf16)b.z; o[7] = (bf16)b.w;
  *(bf16x8*)(d + i) = o;
}

// ---------- W_qkv convert with softmax scale pre-folded into Q rows ----------
__global__ __launch_bounds__(256) void cvt_wqkv(const float* __restrict__ s,
                                                bf16* __restrict__ d, int n) {
  int i = (blockIdx.x * 256 + threadIdx.x) * 8;
  if (i >= n) return;
  int row = i >> 10;  // D=1024 per row
  float sc = ((row % 192) < 64) ? 0.18033688011f : 1.0f;
  const float4* p = (const float4*)(s + i);
  float4 a = p[0], b = p[1];
  bf16x8 o;
  o[0] = (bf16)(a.x * sc); o[1] = (bf16)(a.y * sc);
  o[2] = (bf16)(a.z * sc); o[3] = (bf16)(a.w * sc);
  o[4] = (bf16)(b.x * sc); o[5] = (bf16)(b.y * sc);
  o[6] = (bf16)(b.z * sc); o[7] = (bf16)(b.w * sc);
  *(bf16x8*)(d + i) = o;
}

// ---------- async global->LDS, 16B per lane ----------
__device__ __forceinline__ void gl_lds16(const bf16* g, bf16* l) {
  __builtin_amdgcn_global_load_lds((gvoid_t*)g, (lvoid_t*)l, 16, 0, 0);
}

// ---------- GEMM: C[m][n] = sum_k A[m][k] * Bt[n][k]  (m97 structure) ----------
template <bool OUT_BF16>
__global__ __launch_bounds__(256) void gemm_bt(const bf16* __restrict__ A,
                                               const bf16* __restrict__ Bt,
                                               void* __restrict__ Cv,
                                               int M, int N, int K) {
  __shared__ bf16 sA[128 * 32];
  __shared__ bf16 sB[128 * 32];
  const int tid = threadIdx.x;
  const int wv = tid >> 6, lane = tid & 63;
  const int wr = wv >> 1, wc = wv & 1;
  const int lrow = lane & 15, lgrp = lane >> 4;
  const int R0 = blockIdx.y * 128, C0 = blockIdx.x * 128;

  floatx4 acc[4][4] = {};

  const bf16* gA = A + (size_t)(R0 + wv * 32 + (lane >> 2)) * K + (lane & 3) * 8;
  const bf16* gB = Bt + (size_t)(C0 + wv * 32 + (lane >> 2)) * K + (lane & 3) * 8;
  bf16* lA = sA + wv * 1024;
  bf16* lB = sB + wv * 1024;
  const size_t rowstep = (size_t)16 * K;

  for (int k0 = 0; k0 < K; k0 += 32) {
    gl_lds16(gA + k0, lA);
    gl_lds16(gA + k0 + rowstep, lA + 512);
    gl_lds16(gB + k0, lB);
    gl_lds16(gB + k0 + rowstep, lB + 512);
    __syncthreads();
    bf16x8 af[4], bfr[4];
#pragma unroll
    for (int i = 0; i < 4; i++)
      af[i] = *(const bf16x8*)&sA[(wr * 64 + i * 16 + lrow) * 32 + lgrp * 8];
#pragma unroll
    for (int j = 0; j < 4; j++)
      bfr[j] = *(const bf16x8*)&sB[(wc * 64 + j * 16 + lrow) * 32 + lgrp * 8];
#pragma unroll
    for (int i = 0; i < 4; i++)
#pragma unroll
      for (int j = 0; j < 4; j++)
        acc[i][j] = MFMA16(af[i], bfr[j], acc[i][j]);
    __syncthreads();
  }

  const int rbase = R0 + wr * 64 + lgrp * 4;
  const int cbase = C0 + wc * 64 + lrow;
  if (OUT_BF16) {
    bf16* C = (bf16*)Cv;
#pragma unroll
    for (int i = 0; i < 4; i++)
#pragma unroll
      for (int j = 0; j < 4; j++)
#pragma unroll
        for (int r = 0; r < 4; r++)
          C[(size_t)(rbase + i * 16 + r) * N + cbase + j * 16] = (bf16)acc[i][j][r];
  } else {
    float* C = (float*)Cv;
#pragma unroll
    for (int i = 0; i < 4; i++)
#pragma unroll
      for (int j = 0; j < 4; j++)
#pragma unroll
        for (int r = 0; r < 4; r++)
          C[(size_t)(rbase + i * 16 + r) * N + cbase + j * 16] = acc[i][j][r];
  }
}

// ---------- V transpose with sigma permutation baked in ----------
__global__ __launch_bounds__(256) void transpose_v(const bf16* __restrict__ qkv,
                                                   bf16* __restrict__ Vt) {
  __shared__ bf16 sT[64 * 72];
  const int tid = threadIdx.x;
  const int b = blockIdx.z, h = blockIdx.y, s0 = blockIdx.x * 64;
  const bf16* vsrc = qkv + (size_t)(b * S_TOK + s0) * E3 + h * 192 + 128;
#pragma unroll
  for (int j = 0; j < 8; j++) {
    int idx = tid + 256 * j;
    int sl = idx & 63, dp = idx >> 6;
    unsigned u = *(const unsigned*)(vsrc + (size_t)sl * E3 + 2 * dp);
    sT[(2 * dp) * 72 + sl] = __builtin_bit_cast(bf16, (unsigned short)(u & 0xffffu));
    sT[(2 * dp + 1) * 72 + sl] = __builtin_bit_cast(bf16, (unsigned short)(u >> 16));
  }
  __syncthreads();
  bf16* vdst = Vt + ((size_t)(b * 16 + h) * 64) * S_TOK + s0;
#pragma unroll
  for (int j = 0; j < 2; j++) {
    int idx = tid + 256 * j;
    int d = idx >> 3, sc8 = (idx & 7) * 8;
    bf16x8 o;
#pragma unroll
    for (int m2 = 0; m2 < 8; m2++) {
      int sp = sc8 + m2;
      int ss = (sp & ~31) | ((sp >> 1) & 15) | ((sp & 1) << 4);
      o[m2] = sT[d * 72 + ss];
    }
    *(bf16x8*)(vdst + (size_t)d * S_TOK + sc8) = o;
  }
}

// ---------- attention v7: m97-style LDS staging, double-buffered ----------
// Block = 256 thr (4 waves) owns 128 q-rows; wave w owns rows [w*32, w*32+32)
// and sees ALL 2048 keys (no cross-wave reduction). K/V staged cooperatively
// per 64-key stage via global_load_lds (16B), double-buffered, ONE barrier
// per stage. XOR swizzle ((lane&7)^(lane>>3)) applied at the staging SOURCE
// so the strided b128 fragment reads are bank-conflict-free (gl_lds16 forces
// contiguous lane->LDS so the swizzle can't be done on the destination).
__global__ __launch_bounds__(256, 3) void attn(const bf16* __restrict__ qkv,
                                               const bf16* __restrict__ Vt,
                                               bf16* __restrict__ vals) {
  __shared__ bf16 sK[2][64 * 64];      // 16 KB  [buf][key][dh] (chunk-swizzled)
  __shared__ bf16 sV[2][64 * 64];      // 16 KB  [buf][dh][key'] (chunk-swizzled)
  __shared__ bf16 sP[4][2][16 * 40];   // 10.25 KB wave-private P round-trip

  const int tid = threadIdx.x;
  const int wv = tid >> 6, lane = tid & 63;
  const int lrow = lane & 15, lgrp = lane >> 4;
  const int b = blockIdx.z, h = blockIdx.y;
  const int qb = blockIdx.x * 128;

  // staging source addressing (swizzle on source side)
  const int srow = lane >> 3;          // 0..7
  const int scol = (lane & 7) ^ srow;  // swizzled 16B-chunk
  const bf16* kg0 = qkv + (size_t)(b * S_TOK + wv * 16 + srow) * E3 + h * 192 + 64 + scol * 8;
  const bf16* vg0 = Vt + (size_t)((b * 16 + h) * 64 + wv * 16 + srow) * S_TOK + scol * 8;

  // Q A-fragments (pre-scaled by 0.125*log2e): A[m=lane&15][k=lgrp*8+j]
  const bf16* qp = qkv + (size_t)(b * S_TOK + qb + wv * 32) * E3 + h * 192;
  bf16x8 qa[2][2];
#pragma unroll
  for (int rt = 0; rt < 2; rt++)
#pragma unroll
    for (int dh = 0; dh < 2; dh++)
      qa[rt][dh] = *(const bf16x8*)(qp + (size_t)(rt * 16 + lrow) * E3 + dh * 32 + lgrp * 8);

  floatx4 O[2][4] = {};
  floatx4 lacc[2] = {};
  bf16x8 ones;
  const bf16 one1 = (bf16)1.0f;
#pragma unroll
  for (int j = 0; j < 8; j++) ones[j] = one1;

  const int xsw = (lrow & 7);  // read-side swizzle key

  auto stage = [&](int buf, int kt) {
    const bf16* kg = kg0 + (size_t)kt * 64 * E3;
    gl_lds16(kg, &sK[buf][wv * 1024]);
    gl_lds16(kg + (size_t)8 * E3, &sK[buf][wv * 1024 + 512]);
    const bf16* vg = vg0 + kt * 64;
    gl_lds16(vg, &sV[buf][wv * 1024]);
    gl_lds16(vg + 8 * S_TOK, &sV[buf][wv * 1024 + 512]);
  };

  auto compute = [&](int buf) {
#pragma unroll
    for (int g = 0; g < 2; g++) {  // two 32-key halves of the 64-key stage
      bf16x8 kf[2][2];
#pragma unroll
      for (int t = 0; t < 2; t++)
#pragma unroll
        for (int dh = 0; dh < 2; dh++)
          kf[t][dh] = *(const bf16x8*)&sK[buf][(g * 32 + t * 16 + lrow) * 64 +
                                              ((dh * 4 + lgrp) ^ xsw) * 8];
      // QK^T, exp2, pack P in A-layout order (sigma cols 2c,2c+1)
#pragma unroll
      for (int rt = 0; rt < 2; rt++) {
        floatx4 sc0 = {0.f, 0.f, 0.f, 0.f}, sc1 = {0.f, 0.f, 0.f, 0.f};
        sc0 = MFMA16(qa[rt][0], kf[0][0], sc0);
        sc0 = MFMA16(qa[rt][1], kf[0][1], sc0);
        sc1 = MFMA16(qa[rt][0], kf[1][0], sc1);
        sc1 = MFMA16(qa[rt][1], kf[1][1], sc1);
#pragma unroll
        for (int r = 0; r < 4; r++) {
          bf16x2 h2;
          h2[0] = (bf16)EXP2(sc0[r]);
          h2[1] = (bf16)EXP2(sc1[r]);
          *(unsigned*)&sP[wv][rt][(lgrp * 4 + r) * 40 + lrow * 2] =
              __builtin_bit_cast(unsigned, h2);
        }
      }
      bf16x8 vf[4];
#pragma unroll
      for (int dt = 0; dt < 4; dt++)
        vf[dt] = *(const bf16x8*)&sV[buf][(dt * 16 + lrow) * 64 +
                                          ((g * 4 + lgrp) ^ xsw) * 8];
#pragma unroll
      for (int rt = 0; rt < 2; rt++) {
        bf16x8 pf = *(const bf16x8*)&sP[wv][rt][lrow * 40 + lgrp * 8];
#pragma unroll
        for (int dt = 0; dt < 4; dt++) O[rt][dt] = MFMA16(pf, vf[dt], O[rt][dt]);
        lacc[rt] = MFMA16(pf, ones, lacc[rt]);
      }
    }
  };

  stage(0, 0);
  __syncthreads();  // stage 0 landed
#pragma unroll 1
  for (int kt = 0; kt < 32; kt += 2) {
    stage(1, kt + 1);  // prefetch into other buffer, overlaps compute below
    compute(0);
    __syncthreads();   // drains prefetch vmcnt + protects buf0 reuse
    if (kt + 2 < 32) stage(0, kt + 2);
    compute(1);
    __syncthreads();
  }

  // epilogue: per-wave normalize + store (no cross-wave reduction needed)
  bf16* vout = vals + (size_t)(b * S_TOK + qb + wv * 32) * DMODEL + h * 64;
#pragma unroll
  for (int rt = 0; rt < 2; rt++)
#pragma unroll
    for (int r = 0; r < 4; r++) {
      float rinv = __builtin_amdgcn_rcpf(lacc[rt][r]);
#pragma unroll
      for (int dt = 0; dt < 4; dt++)
        vout[(size_t)(rt * 16 + lgrp * 4 + r) * DMODEL + dt * 16 + lrow] =
            (bf16)(O[rt][dt][r] * rinv);
    }
}

// ---------- host ----------
extern "C" void kernel_launch(void* const* d_in, const int* in_sizes, int n_in,
                              void* d_out, int out_size, void* d_ws, size_t ws_size,
                              hipStream_t stream) {
  const float* X = (const float*)d_in[0];     // (2,2048,1024)
  const float* Wqkv = (const float*)d_in[1];  // (3072,1024)
  const float* Wout = (const float*)d_in[2];  // (1024,1024)
  float* out = (float*)d_out;                 // (2,2048,1024)

  char* ws = (char*)d_ws;
  bf16* Xb = (bf16*)(ws);                          //  8 MB
  bf16* Wqb = (bf16*)(ws + ((size_t)8 << 20));     //  6 MB
  bf16* Wob = (bf16*)(ws + ((size_t)14 << 20));    //  2 MB
  bf16* qkvb = (bf16*)(ws + ((size_t)16 << 20));   // 24 MB (4096 x 3072)
  bf16* Vt = (bf16*)(ws + ((size_t)40 << 20));     //  8 MB (2*16*64 x 2048)
  bf16* vals = (bf16*)(ws + ((size_t)48 << 20));   //  8 MB (4096 x 1024)

  cvt_f32_bf16<<<4194304 / 2048, 256, 0, stream>>>(X, Xb, 4194304);
  cvt_wqkv<<<3145728 / 2048, 256, 0, stream>>>(Wqkv, Wqb, 3145728);
  cvt_f32_bf16<<<1048576 / 2048, 256, 0, stream>>>(Wout, Wob, 1048576);

  // qkv = X @ Wqkv^T : (4096,1024)x(3072,1024)^T -> (4096,3072) bf16
  gemm_bt<true><<<dim3(24, 32), 256, 0, stream>>>(Xb, Wqb, qkvb, 4096, 3072, 1024);

  transpose_v<<<dim3(32, 16, 2), 256, 0, stream>>>(qkvb, Vt);

  attn<<<dim3(16, 16, 2), 256, 0, stream>>>(qkvb, Vt, vals);

  // out = vals @ Wout^T : (4096,1024)x(1024,1024)^T -> (4096,1024) fp32
  gemm_bt<false><<<dim3(8, 32), 256, 0, stream>>>(vals, Wob, out, 4096, 1024, 1024);
}

// Round 9
// 186.871 us; speedup vs baseline: 1.4672x; 1.0858x over previous
//
#include <hip/hip_runtime.h>
#include <cstdint>
#include <cstddef>

// ---------- types ----------
typedef __bf16 bf16;
typedef __bf16 bf16x8 __attribute__((ext_vector_type(8)));
typedef __bf16 bf16x2 __attribute__((ext_vector_type(2)));
typedef float  floatx4 __attribute__((ext_vector_type(4)));

typedef __attribute__((address_space(1))) void gvoid_t;
typedef __attribute__((address_space(3))) void lvoid_t;

#define MFMA16(a, b, c) __builtin_amdgcn_mfma_f32_16x16x32_bf16((a), (b), (c), 0, 0, 0)

#if __has_builtin(__builtin_amdgcn_exp2f)
#define EXP2(x) __builtin_amdgcn_exp2f(x)
#else
#define EXP2(x) exp2f(x)
#endif

// B=2, S=2048, D=1024, H=16, DH=64; tokens NT=4096; E3=3072
#define S_TOK 2048
#define E3 3072
#define DMODEL 1024

// ---------- fused fp32 -> bf16 convert (X, Wqkv w/ Q-scale, Wout) ----------
#define NX 4194304
#define NWQ 3145728
#define NWO 1048576
__global__ __launch_bounds__(256) void cvt_all(const float* __restrict__ X,
                                               const float* __restrict__ Wq,
                                               const float* __restrict__ Wo,
                                               bf16* __restrict__ Xb,
                                               bf16* __restrict__ Wqb,
                                               bf16* __restrict__ Wob) {
  int i = (blockIdx.x * 256 + threadIdx.x) * 8;
  const float* s;
  bf16* d;
  float sc = 1.0f;
  int off;
  if (i < NX) {
    s = X; d = Xb; off = i;
  } else if (i < NX + NWQ) {
    off = i - NX; s = Wq; d = Wqb;
    int row = off >> 10;  // D=1024 per row; rows with e%192<64 produce Q
    if ((row % 192) < 64) sc = 0.18033688011f;  // 0.125*log2(e) pre-folded
  } else {
    off = i - NX - NWQ; s = Wo; d = Wob;
  }
  const float4* p = (const float4*)(s + off);
  float4 a = p[0], b = p[1];
  bf16x8 o;
  o[0] = (bf16)(a.x * sc); o[1] = (bf16)(a.y * sc);
  o[2] = (bf16)(a.z * sc); o[3] = (bf16)(a.w * sc);
  o[4] = (bf16)(b.x * sc); o[5] = (bf16)(b.y * sc);
  o[6] = (bf16)(b.z * sc); o[7] = (bf16)(b.w * sc);
  *(bf16x8*)(d + off) = o;
}

// ---------- async global->LDS, 16B per lane ----------
__device__ __forceinline__ void gl_lds16(const bf16* g, bf16* l) {
  __builtin_amdgcn_global_load_lds((gvoid_t*)g, (lvoid_t*)l, 16, 0, 0);
}

// ---------- GEMM v2: BK=64, XOR-swizzled LDS, half the barriers ----------
// C[m][n] = sum_k A[m][k]*Bt[n][k]. 128x128 tile, 4 waves 2x2, wave 64x64.
// LDS rows are 64 elems (128B); chunk c of row r stored at c^(r&7) so the
// 16-lane b128 fragment reads are 2-way (free) instead of 16-way (5.7x).
// Swizzle applied at the staging SOURCE (gl_lds16 dest is lane-contiguous).
template <bool OUT_BF16>
__global__ __launch_bounds__(256) void gemm_bt(const bf16* __restrict__ A,
                                               const bf16* __restrict__ Bt,
                                               void* __restrict__ Cv,
                                               int M, int N, int K) {
  __shared__ bf16 sA[128 * 64];  // 16 KB
  __shared__ bf16 sB[128 * 64];  // 16 KB
  const int tid = threadIdx.x;
  const int wv = tid >> 6, lane = tid & 63;
  const int wr = wv >> 1, wc = wv & 1;
  const int lrow = lane & 15, lgrp = lane >> 4;
  const int R0 = blockIdx.y * 128, C0 = blockIdx.x * 128;

  floatx4 acc[4][4] = {};

  // staging: wave covers rows [wv*32, wv*32+32) in 4 chunks of 8 rows;
  // lane = srow*8 + schk; source col-chunk is XOR-swizzled by row
  const int srow = lane >> 3;
  const int schk = (lane & 7) ^ srow;  // swizzle key = srow&7 (= srow here)
  const bf16* gA = A + (size_t)(R0 + wv * 32 + srow) * K + schk * 8;
  const bf16* gB = Bt + (size_t)(C0 + wv * 32 + srow) * K + schk * 8;
  bf16* lA = sA + wv * 32 * 64;
  bf16* lB = sB + wv * 32 * 64;
  const size_t rs8 = (size_t)8 * K;

  for (int k0 = 0; k0 < K; k0 += 64) {
#pragma unroll
    for (int c = 0; c < 4; c++) {
      gl_lds16(gA + k0 + c * rs8, lA + c * 512);
      gl_lds16(gB + k0 + c * rs8, lB + c * 512);
    }
    __syncthreads();  // stage landed
#pragma unroll
    for (int kk = 0; kk < 2; kk++) {
      bf16x8 af[4], bfr[4];
#pragma unroll
      for (int i = 0; i < 4; i++) {
        int r = wr * 64 + i * 16 + lrow;
        af[i] = *(const bf16x8*)&sA[r * 64 + ((kk * 4 + lgrp) ^ (r & 7)) * 8];
      }
#pragma unroll
      for (int j = 0; j < 4; j++) {
        int r = wc * 64 + j * 16 + lrow;
        bfr[j] = *(const bf16x8*)&sB[r * 64 + ((kk * 4 + lgrp) ^ (r & 7)) * 8];
      }
#pragma unroll
      for (int i = 0; i < 4; i++)
#pragma unroll
        for (int j = 0; j < 4; j++)
          acc[i][j] = MFMA16(af[i], bfr[j], acc[i][j]);
    }
    __syncthreads();  // all reads done before restage
  }

  const int rbase = R0 + wr * 64 + lgrp * 4;
  const int cbase = C0 + wc * 64 + lrow;
  if (OUT_BF16) {
    bf16* C = (bf16*)Cv;
#pragma unroll
    for (int i = 0; i < 4; i++)
#pragma unroll
      for (int j = 0; j < 4; j++)
#pragma unroll
        for (int r = 0; r < 4; r++)
          C[(size_t)(rbase + i * 16 + r) * N + cbase + j * 16] = (bf16)acc[i][j][r];
  } else {
    float* C = (float*)Cv;
#pragma unroll
    for (int i = 0; i < 4; i++)
#pragma unroll
      for (int j = 0; j < 4; j++)
#pragma unroll
        for (int r = 0; r < 4; r++)
          C[(size_t)(rbase + i * 16 + r) * N + cbase + j * 16] = acc[i][j][r];
  }
}

// ---------- V transpose with sigma permutation baked in ----------
__global__ __launch_bounds__(256) void transpose_v(const bf16* __restrict__ qkv,
                                                   bf16* __restrict__ Vt) {
  __shared__ bf16 sT[64 * 72];
  const int tid = threadIdx.x;
  const int b = blockIdx.z, h = blockIdx.y, s0 = blockIdx.x * 64;
  const bf16* vsrc = qkv + (size_t)(b * S_TOK + s0) * E3 + h * 192 + 128;
#pragma unroll
  for (int j = 0; j < 8; j++) {
    int idx = tid + 256 * j;
    int sl = idx & 63, dp = idx >> 6;
    unsigned u = *(const unsigned*)(vsrc + (size_t)sl * E3 + 2 * dp);
    sT[(2 * dp) * 72 + sl] = __builtin_bit_cast(bf16, (unsigned short)(u & 0xffffu));
    sT[(2 * dp + 1) * 72 + sl] = __builtin_bit_cast(bf16, (unsigned short)(u >> 16));
  }
  __syncthreads();
  bf16* vdst = Vt + ((size_t)(b * 16 + h) * 64) * S_TOK + s0;
#pragma unroll
  for (int j = 0; j < 2; j++) {
    int idx = tid + 256 * j;
    int d = idx >> 3, sc8 = (idx & 7) * 8;
    bf16x8 o;
#pragma unroll
    for (int m2 = 0; m2 < 8; m2++) {
      int sp = sc8 + m2;
      int ss = (sp & ~31) | ((sp >> 1) & 15) | ((sp & 1) << 4);
      o[m2] = sT[d * 72 + ss];
    }
    *(bf16x8*)(vdst + (size_t)d * S_TOK + sc8) = o;
  }
}

// ---------- attention v7 (unchanged from R8 — the control) ----------
__global__ __launch_bounds__(256, 3) void attn(const bf16* __restrict__ qkv,
                                               const bf16* __restrict__ Vt,
                                               bf16* __restrict__ vals) {
  __shared__ bf16 sK[2][64 * 64];      // 16 KB  [buf][key][dh] (chunk-swizzled)
  __shared__ bf16 sV[2][64 * 64];      // 16 KB  [buf][dh][key'] (chunk-swizzled)
  __shared__ bf16 sP[4][2][16 * 40];   // 10.25 KB wave-private P round-trip

  const int tid = threadIdx.x;
  const int wv = tid >> 6, lane = tid & 63;
  const int lrow = lane & 15, lgrp = lane >> 4;
  const int b = blockIdx.z, h = blockIdx.y;
  const int qb = blockIdx.x * 128;

  const int srow = lane >> 3;
  const int scol = (lane & 7) ^ srow;
  const bf16* kg0 = qkv + (size_t)(b * S_TOK + wv * 16 + srow) * E3 + h * 192 + 64 + scol * 8;
  const bf16* vg0 = Vt + (size_t)((b * 16 + h) * 64 + wv * 16 + srow) * S_TOK + scol * 8;

  const bf16* qp = qkv + (size_t)(b * S_TOK + qb + wv * 32) * E3 + h * 192;
  bf16x8 qa[2][2];
#pragma unroll
  for (int rt = 0; rt < 2; rt++)
#pragma unroll
    for (int dh = 0; dh < 2; dh++)
      qa[rt][dh] = *(const bf16x8*)(qp + (size_t)(rt * 16 + lrow) * E3 + dh * 32 + lgrp * 8);

  floatx4 O[2][4] = {};
  floatx4 lacc[2] = {};
  bf16x8 ones;
  const bf16 one1 = (bf16)1.0f;
#pragma unroll
  for (int j = 0; j < 8; j++) ones[j] = one1;

  const int xsw = (lrow & 7);

  auto stage = [&](int buf, int kt) {
    const bf16* kg = kg0 + (size_t)kt * 64 * E3;
    gl_lds16(kg, &sK[buf][wv * 1024]);
    gl_lds16(kg + (size_t)8 * E3, &sK[buf][wv * 1024 + 512]);
    const bf16* vg = vg0 + kt * 64;
    gl_lds16(vg, &sV[buf][wv * 1024]);
    gl_lds16(vg + 8 * S_TOK, &sV[buf][wv * 1024 + 512]);
  };

  auto compute = [&](int buf) {
#pragma unroll
    for (int g = 0; g < 2; g++) {
      bf16x8 kf[2][2];
#pragma unroll
      for (int t = 0; t < 2; t++)
#pragma unroll
        for (int dh = 0; dh < 2; dh++)
          kf[t][dh] = *(const bf16x8*)&sK[buf][(g * 32 + t * 16 + lrow) * 64 +
                                              ((dh * 4 + lgrp) ^ xsw) * 8];
#pragma unroll
      for (int rt = 0; rt < 2; rt++) {
        floatx4 sc0 = {0.f, 0.f, 0.f, 0.f}, sc1 = {0.f, 0.f, 0.f, 0.f};
        sc0 = MFMA16(qa[rt][0], kf[0][0], sc0);
        sc0 = MFMA16(qa[rt][1], kf[0][1], sc0);
        sc1 = MFMA16(qa[rt][0], kf[1][0], sc1);
        sc1 = MFMA16(qa[rt][1], kf[1][1], sc1);
#pragma unroll
        for (int r = 0; r < 4; r++) {
          bf16x2 h2;
          h2[0] = (bf16)EXP2(sc0[r]);
          h2[1] = (bf16)EXP2(sc1[r]);
          *(unsigned*)&sP[wv][rt][(lgrp * 4 + r) * 40 + lrow * 2] =
              __builtin_bit_cast(unsigned, h2);
        }
      }
      bf16x8 vf[4];
#pragma unroll
      for (int dt = 0; dt < 4; dt++)
        vf[dt] = *(const bf16x8*)&sV[buf][(dt * 16 + lrow) * 64 +
                                          ((g * 4 + lgrp) ^ xsw) * 8];
#pragma unroll
      for (int rt = 0; rt < 2; rt++) {
        bf16x8 pf = *(const bf16x8*)&sP[wv][rt][lrow * 40 + lgrp * 8];
#pragma unroll
        for (int dt = 0; dt < 4; dt++) O[rt][dt] = MFMA16(pf, vf[dt], O[rt][dt]);
        lacc[rt] = MFMA16(pf, ones, lacc[rt]);
      }
    }
  };

  stage(0, 0);
  __syncthreads();
#pragma unroll 1
  for (int kt = 0; kt < 32; kt += 2) {
    stage(1, kt + 1);
    compute(0);
    __syncthreads();
    if (kt + 2 < 32) stage(0, kt + 2);
    compute(1);
    __syncthreads();
  }

  bf16* vout = vals + (size_t)(b * S_TOK + qb + wv * 32) * DMODEL + h * 64;
#pragma unroll
  for (int rt = 0; rt < 2; rt++)
#pragma unroll
    for (int r = 0; r < 4; r++) {
      float rinv = __builtin_amdgcn_rcpf(lacc[rt][r]);
#pragma unroll
      for (int dt = 0; dt < 4; dt++)
        vout[(size_t)(rt * 16 + lgrp * 4 + r) * DMODEL + dt * 16 + lrow] =
            (bf16)(O[rt][dt][r] * rinv);
    }
}

// ---------- host ----------
extern "C" void kernel_launch(void* const* d_in, const int* in_sizes, int n_in,
                              void* d_out, int out_size, void* d_ws, size_t ws_size,
                              hipStream_t stream) {
  const float* X = (const float*)d_in[0];     // (2,2048,1024)
  const float* Wqkv = (const float*)d_in[1];  // (3072,1024)
  const float* Wout = (const float*)d_in[2];  // (1024,1024)
  float* out = (float*)d_out;                 // (2,2048,1024)

  char* ws = (char*)d_ws;
  bf16* Xb = (bf16*)(ws);                          //  8 MB
  bf16* Wqb = (bf16*)(ws + ((size_t)8 << 20));     //  6 MB
  bf16* Wob = (bf16*)(ws + ((size_t)14 << 20));    //  2 MB
  bf16* qkvb = (bf16*)(ws + ((size_t)16 << 20));   // 24 MB (4096 x 3072)
  bf16* Vt = (bf16*)(ws + ((size_t)40 << 20));     //  8 MB (2*16*64 x 2048)
  bf16* vals = (bf16*)(ws + ((size_t)48 << 20));   //  8 MB (4096 x 1024)

  cvt_all<<<(NX + NWQ + NWO) / 2048, 256, 0, stream>>>(X, Wqkv, Wout, Xb, Wqb, Wob);

  // qkv = X @ Wqkv^T : (4096,1024)x(3072,1024)^T -> (4096,3072) bf16
  gemm_bt<true><<<dim3(24, 32), 256, 0, stream>>>(Xb, Wqb, qkvb, 4096, 3072, 1024);

  transpose_v<<<dim3(32, 16, 2), 256, 0, stream>>>(qkvb, Vt);

  attn<<<dim3(16, 16, 2), 256, 0, stream>>>(qkvb, Vt, vals);

  // out = vals @ Wout^T : (4096,1024)x(1024,1024)^T -> (4096,1024) fp32
  gemm_bt<false><<<dim3(8, 32), 256, 0, stream>>>(vals, Wob, out, 4096, 1024, 1024);
}

// Round 10
// 179.991 us; speedup vs baseline: 1.5233x; 1.0382x over previous
//
#include <hip/hip_runtime.h>
#include <cstdint>
#include <cstddef>

// ---------- types ----------
typedef __bf16 bf16;
typedef __bf16 bf16x8 __attribute__((ext_vector_type(8)));
typedef __bf16 bf16x2 __attribute__((ext_vector_type(2)));
typedef float  floatx4 __attribute__((ext_vector_type(4)));

typedef __attribute__((address_space(1))) void gvoid_t;
typedef __attribute__((address_space(3))) void lvoid_t;

#define MFMA16(a, b, c) __builtin_amdgcn_mfma_f32_16x16x32_bf16((a), (b), (c), 0, 0, 0)

#if __has_builtin(__builtin_amdgcn_exp2f)
#define EXP2(x) __builtin_amdgcn_exp2f(x)
#else
#define EXP2(x) exp2f(x)
#endif

// B=2, S=2048, D=1024, H=16, DH=64; tokens NT=4096; E3=3072
#define S_TOK 2048
#define E3 3072
#define DMODEL 1024

// ---------- fused fp32 -> bf16 convert (X, Wqkv w/ Q-scale, Wout) ----------
#define NX 4194304
#define NWQ 3145728
#define NWO 1048576
__global__ __launch_bounds__(256) void cvt_all(const float* __restrict__ X,
                                               const float* __restrict__ Wq,
                                               const float* __restrict__ Wo,
                                               bf16* __restrict__ Xb,
                                               bf16* __restrict__ Wqb,
                                               bf16* __restrict__ Wob) {
  int i = (blockIdx.x * 256 + threadIdx.x) * 8;
  const float* s;
  bf16* d;
  float sc = 1.0f;
  int off;
  if (i < NX) {
    s = X; d = Xb; off = i;
  } else if (i < NX + NWQ) {
    off = i - NX; s = Wq; d = Wqb;
    int row = off >> 10;  // D=1024 per row; rows with e%192<64 produce Q
    if ((row % 192) < 64) sc = 0.18033688011f;  // 0.125*log2(e) pre-folded
  } else {
    off = i - NX - NWQ; s = Wo; d = Wob;
  }
  const float4* p = (const float4*)(s + off);
  float4 a = p[0], b = p[1];
  bf16x8 o;
  o[0] = (bf16)(a.x * sc); o[1] = (bf16)(a.y * sc);
  o[2] = (bf16)(a.z * sc); o[3] = (bf16)(a.w * sc);
  o[4] = (bf16)(b.x * sc); o[5] = (bf16)(b.y * sc);
  o[6] = (bf16)(b.z * sc); o[7] = (bf16)(b.w * sc);
  *(bf16x8*)(d + off) = o;
}

// ---------- async global->LDS, 16B per lane ----------
__device__ __forceinline__ void gl_lds16(const bf16* g, bf16* l) {
  __builtin_amdgcn_global_load_lds((gvoid_t*)g, (lvoid_t*)l, 16, 0, 0);
}

// ---------- GEMM: BK=64, XOR-swizzled LDS; optional fused V-transpose ----------
// C[m][n] = sum_k A[m][k]*Bt[n][k]. 128x128 tile, 4 waves 2x2, wave 64x64.
// FUSE_V (QKV gemm): cols with e%192>=128 are V -> written straight to Vt with
// the sigma permutation (sp = (s&~31)|((s&15)<<1)|((s>>4)&1)) via a branchless
// address select; deletes the separate transpose_v kernel.
template <bool OUT_BF16, bool FUSE_V>
__global__ __launch_bounds__(256) void gemm_bt(const bf16* __restrict__ A,
                                               const bf16* __restrict__ Bt,
                                               void* __restrict__ Cv,
                                               bf16* __restrict__ Vt,
                                               int M, int N, int K) {
  __shared__ bf16 sA[128 * 64];  // 16 KB
  __shared__ bf16 sB[128 * 64];  // 16 KB
  const int tid = threadIdx.x;
  const int wv = tid >> 6, lane = tid & 63;
  const int wr = wv >> 1, wc = wv & 1;
  const int lrow = lane & 15, lgrp = lane >> 4;
  const int R0 = blockIdx.y * 128, C0 = blockIdx.x * 128;

  floatx4 acc[4][4] = {};

  const int srow = lane >> 3;
  const int schk = (lane & 7) ^ srow;  // source chunk, swizzle key = row&7
  const bf16* gA = A + (size_t)(R0 + wv * 32 + srow) * K + schk * 8;
  const bf16* gB = Bt + (size_t)(C0 + wv * 32 + srow) * K + schk * 8;
  bf16* lA = sA + wv * 32 * 64;
  bf16* lB = sB + wv * 32 * 64;
  const size_t rs8 = (size_t)8 * K;

  for (int k0 = 0; k0 < K; k0 += 64) {
#pragma unroll
    for (int c = 0; c < 4; c++) {
      gl_lds16(gA + k0 + c * rs8, lA + c * 512);
      gl_lds16(gB + k0 + c * rs8, lB + c * 512);
    }
    __syncthreads();
#pragma unroll
    for (int kk = 0; kk < 2; kk++) {
      bf16x8 af[4], bfr[4];
#pragma unroll
      for (int i = 0; i < 4; i++) {
        int r = wr * 64 + i * 16 + lrow;
        af[i] = *(const bf16x8*)&sA[r * 64 + ((kk * 4 + lgrp) ^ (r & 7)) * 8];
      }
#pragma unroll
      for (int j = 0; j < 4; j++) {
        int r = wc * 64 + j * 16 + lrow;
        bfr[j] = *(const bf16x8*)&sB[r * 64 + ((kk * 4 + lgrp) ^ (r & 7)) * 8];
      }
#pragma unroll
      for (int i = 0; i < 4; i++)
#pragma unroll
        for (int j = 0; j < 4; j++)
          acc[i][j] = MFMA16(af[i], bfr[j], acc[i][j]);
    }
    __syncthreads();
  }

  const int rbase = R0 + wr * 64 + lgrp * 4;
  const int cbase = C0 + wc * 64 + lrow;
  if (OUT_BF16) {
    bf16* C = (bf16*)Cv;
#pragma unroll
    for (int i = 0; i < 4; i++)
#pragma unroll
      for (int j = 0; j < 4; j++) {
        const int col = cbase + j * 16;
        const int m192 = col % 192;
        const int hh = col / 192;
#pragma unroll
        for (int r = 0; r < 4; r++) {
          const int row = rbase + i * 16 + r;
          bf16 val = (bf16)acc[i][j][r];
          bf16* dst;
          if (FUSE_V && m192 >= 128) {
            const int sl = row & 2047;
            const int sp = (sl & ~31) | ((sl & 15) << 1) | ((sl >> 4) & 1);
            dst = Vt + ((size_t)(((row >> 11) * 16 + hh) * 64 + (m192 - 128))) * S_TOK + sp;
          } else {
            dst = C + (size_t)row * N + col;
          }
          *dst = val;
        }
      }
  } else {
    float* C = (float*)Cv;
#pragma unroll
    for (int i = 0; i < 4; i++)
#pragma unroll
      for (int j = 0; j < 4; j++)
#pragma unroll
        for (int r = 0; r < 4; r++)
          C[(size_t)(rbase + i * 16 + r) * N + cbase + j * 16] = acc[i][j][r];
  }
}

// ---------- GEMM 128x64 tile (out-proj: N=1024 -> 512 blocks, 2/CU) ----------
__global__ __launch_bounds__(256) void gemm_bt_n64(const bf16* __restrict__ A,
                                                   const bf16* __restrict__ Bt,
                                                   float* __restrict__ C,
                                                   int M, int N, int K) {
  __shared__ bf16 sA[128 * 64];  // 16 KB
  __shared__ bf16 sB[64 * 64];   //  8 KB
  const int tid = threadIdx.x;
  const int wv = tid >> 6, lane = tid & 63;
  const int wr = wv >> 1, wc = wv & 1;
  const int lrow = lane & 15, lgrp = lane >> 4;
  const int R0 = blockIdx.y * 128, C0 = blockIdx.x * 64;

  floatx4 acc[4][2] = {};

  const int srow = lane >> 3;
  const int schk = (lane & 7) ^ srow;
  const bf16* gA = A + (size_t)(R0 + wv * 32 + srow) * K + schk * 8;
  const bf16* gB = Bt + (size_t)(C0 + wv * 16 + srow) * K + schk * 8;
  bf16* lA = sA + wv * 32 * 64;
  bf16* lB = sB + wv * 16 * 64;
  const size_t rs8 = (size_t)8 * K;

  for (int k0 = 0; k0 < K; k0 += 64) {
#pragma unroll
    for (int c = 0; c < 4; c++) gl_lds16(gA + k0 + c * rs8, lA + c * 512);
#pragma unroll
    for (int c = 0; c < 2; c++) gl_lds16(gB + k0 + c * rs8, lB + c * 512);
    __syncthreads();
#pragma unroll
    for (int kk = 0; kk < 2; kk++) {
      bf16x8 af[4], bfr[2];
#pragma unroll
      for (int i = 0; i < 4; i++) {
        int r = wr * 64 + i * 16 + lrow;
        af[i] = *(const bf16x8*)&sA[r * 64 + ((kk * 4 + lgrp) ^ (r & 7)) * 8];
      }
#pragma unroll
      for (int j = 0; j < 2; j++) {
        int r = wc * 32 + j * 16 + lrow;
        bfr[j] = *(const bf16x8*)&sB[r * 64 + ((kk * 4 + lgrp) ^ (r & 7)) * 8];
      }
#pragma unroll
      for (int i = 0; i < 4; i++)
#pragma unroll
        for (int j = 0; j < 2; j++)
          acc[i][j] = MFMA16(af[i], bfr[j], acc[i][j]);
    }
    __syncthreads();
  }

  const int rbase = R0 + wr * 64 + lgrp * 4;
  const int cbase = C0 + wc * 32 + lrow;
#pragma unroll
  for (int i = 0; i < 4; i++)
#pragma unroll
    for (int j = 0; j < 2; j++)
#pragma unroll
      for (int r = 0; r < 4; r++)
        C[(size_t)(rbase + i * 16 + r) * N + cbase + j * 16] = acc[i][j][r];
}

// ---------- attention v8: 8-wave blocks for 16 waves/CU ----------
// Block = 512 thr (8 waves) owns 128 q-rows; wave w owns rows [w*16, w*16+16)
// and sees ALL 2048 keys. K/V staged cooperatively per 64-key stage via
// global_load_lds (1 K + 1 V load per thread), double-buffered, XOR source
// swizzle for conflict-free b128 fragment reads. 512 blocks x 8 waves =
// 4096 waves = 16/CU (R8's 256-thr version was grid-capped at 8/CU, occ 18%).
__global__ __launch_bounds__(512, 4) void attn(const bf16* __restrict__ qkv,
                                               const bf16* __restrict__ Vt,
                                               bf16* __restrict__ vals) {
  __shared__ bf16 sK[2][64 * 64];   // 16 KB [buf][key][dh] (chunk-swizzled)
  __shared__ bf16 sV[2][64 * 64];   // 16 KB [buf][dh][key'] (chunk-swizzled)
  __shared__ bf16 sP[8 * 640];      // 10.25 KB wave-private P round-trip

  const int tid = threadIdx.x;
  const int wv = tid >> 6, lane = tid & 63;
  const int lrow = lane & 15, lgrp = lane >> 4;
  const int b = blockIdx.z, h = blockIdx.y;
  const int qb = blockIdx.x * 128;

  // staging: wave w covers slab rows [w*8, w*8+8); lane = srow*8 + chunk-pos
  const int srow = lane >> 3;
  const int scol = (lane & 7) ^ srow;  // swizzled source chunk
  const bf16* kg0 = qkv + (size_t)(b * S_TOK + wv * 8 + srow) * E3 + h * 192 + 64 + scol * 8;
  const bf16* vg0 = Vt + (size_t)((b * 16 + h) * 64 + wv * 8 + srow) * S_TOK + scol * 8;

  // Q A-fragments (pre-scaled by 0.125*log2e): A[m=lane&15][k=lgrp*8+j]
  const bf16* qp = qkv + (size_t)(b * S_TOK + qb + wv * 16) * E3 + h * 192;
  bf16x8 qa[2];
#pragma unroll
  for (int dh = 0; dh < 2; dh++)
    qa[dh] = *(const bf16x8*)(qp + (size_t)lrow * E3 + dh * 32 + lgrp * 8);

  floatx4 O[4] = {};
  floatx4 lacc = {};
  bf16x8 ones;
  const bf16 one1 = (bf16)1.0f;
#pragma unroll
  for (int j = 0; j < 8; j++) ones[j] = one1;

  const int xsw = (lrow & 7);
  bf16* sPw = sP + wv * 640;

  auto stage = [&](int buf, int kt) {
    gl_lds16(kg0 + (size_t)kt * 64 * E3, &sK[buf][wv * 512]);
    gl_lds16(vg0 + kt * 64, &sV[buf][wv * 512]);
  };

  auto compute = [&](int buf) {
#pragma unroll
    for (int g = 0; g < 2; g++) {  // two 32-key halves of the 64-key stage
      bf16x8 kf[2][2];
#pragma unroll
      for (int t = 0; t < 2; t++)
#pragma unroll
        for (int dh = 0; dh < 2; dh++)
          kf[t][dh] = *(const bf16x8*)&sK[buf][(g * 32 + t * 16 + lrow) * 64 +
                                              ((dh * 4 + lgrp) ^ xsw) * 8];
      floatx4 sc0 = {0.f, 0.f, 0.f, 0.f}, sc1 = {0.f, 0.f, 0.f, 0.f};
      sc0 = MFMA16(qa[0], kf[0][0], sc0);
      sc0 = MFMA16(qa[1], kf[0][1], sc0);
      sc1 = MFMA16(qa[0], kf[1][0], sc1);
      sc1 = MFMA16(qa[1], kf[1][1], sc1);
#pragma unroll
      for (int r = 0; r < 4; r++) {
        bf16x2 h2;
        h2[0] = (bf16)EXP2(sc0[r]);
        h2[1] = (bf16)EXP2(sc1[r]);
        *(unsigned*)&sPw[(lgrp * 4 + r) * 40 + lrow * 2] =
            __builtin_bit_cast(unsigned, h2);
      }
      bf16x8 vf[4];
#pragma unroll
      for (int dt = 0; dt < 4; dt++)
        vf[dt] = *(const bf16x8*)&sV[buf][(dt * 16 + lrow) * 64 +
                                          ((g * 4 + lgrp) ^ xsw) * 8];
      bf16x8 pf = *(const bf16x8*)&sPw[lrow * 40 + lgrp * 8];
#pragma unroll
      for (int dt = 0; dt < 4; dt++) O[dt] = MFMA16(pf, vf[dt], O[dt]);
      lacc = MFMA16(pf, ones, lacc);
    }
  };

  stage(0, 0);
  __syncthreads();
#pragma unroll 1
  for (int kt = 0; kt < 32; kt += 2) {
    stage(1, kt + 1);
    compute(0);
    __syncthreads();
    if (kt + 2 < 32) stage(0, kt + 2);
    compute(1);
    __syncthreads();
  }

  bf16* vout = vals + (size_t)(b * S_TOK + qb + wv * 16) * DMODEL + h * 64;
#pragma unroll
  for (int r = 0; r < 4; r++) {
    float rinv = __builtin_amdgcn_rcpf(lacc[r]);
#pragma unroll
    for (int dt = 0; dt < 4; dt++)
      vout[(size_t)(lgrp * 4 + r) * DMODEL + dt * 16 + lrow] =
          (bf16)(O[dt][r] * rinv);
  }
}

// ---------- host ----------
extern "C" void kernel_launch(void* const* d_in, const int* in_sizes, int n_in,
                              void* d_out, int out_size, void* d_ws, size_t ws_size,
                              hipStream_t stream) {
  const float* X = (const float*)d_in[0];     // (2,2048,1024)
  const float* Wqkv = (const float*)d_in[1];  // (3072,1024)
  const float* Wout = (const float*)d_in[2];  // (1024,1024)
  float* out = (float*)d_out;                 // (2,2048,1024)

  char* ws = (char*)d_ws;
  bf16* Xb = (bf16*)(ws);                          //  8 MB
  bf16* Wqb = (bf16*)(ws + ((size_t)8 << 20));     //  6 MB
  bf16* Wob = (bf16*)(ws + ((size_t)14 << 20));    //  2 MB
  bf16* qkvb = (bf16*)(ws + ((size_t)16 << 20));   // 24 MB (4096 x 3072; V-part unused)
  bf16* Vt = (bf16*)(ws + ((size_t)40 << 20));     //  8 MB (2*16*64 x 2048)
  bf16* vals = (bf16*)(ws + ((size_t)48 << 20));   //  8 MB (4096 x 1024)

  cvt_all<<<(NX + NWQ + NWO) / 2048, 256, 0, stream>>>(X, Wqkv, Wout, Xb, Wqb, Wob);

  // qkv = X @ Wqkv^T, V-part written straight to Vt (sigma-permuted)
  gemm_bt<true, true><<<dim3(24, 32), 256, 0, stream>>>(Xb, Wqb, qkvb, Vt, 4096, 3072, 1024);

  attn<<<dim3(16, 16, 2), 512, 0, stream>>>(qkvb, Vt, vals);

  // out = vals @ Wout^T : 128x64 tiles -> 512 blocks (2/CU)
  gemm_bt_n64<<<dim3(16, 32), 256, 0, stream>>>(vals, Wob, out, 4096, 1024, 1024);
}